// Round 4
// baseline (236.698 us; speedup 1.0000x reference)
//
#include <hip/hip_runtime.h>
#include <math.h>

// Problem constants (B=4, S=4096, D=2048, E=64, K=2)
#define BS_TOT 16384
#define DDIM   2048
#define NEXP   64
#define TOPK   2

#define RPB    32                 // rows per block
#define NWV    4                  // waves per block (split M x E, full K per wave)
#define KTILE  32                 // k per staged tile
#define NKT    (DDIM / KTILE)     // 64 tiles
#define XBYTES (RPB * KTILE * 4)  // 4 KB  x tile (fp32)
#define WBYTES (NEXP * KTILE * 4) // 8 KB  W tile (hi+lo fp16)
#define TBYTES (XBYTES + WBYTES)  // 12 KB per buffer
#define PADE   68

typedef _Float16 half8   __attribute__((ext_vector_type(8)));
typedef float    floatx4 __attribute__((ext_vector_type(4)));

__device__ __forceinline__ void gload_lds16(const void* g, void* l) {
    __builtin_amdgcn_global_load_lds(
        (const __attribute__((address_space(1))) unsigned int*)g,
        (__attribute__((address_space(3))) unsigned int*)l, 16, 0, 0);
}

// ---------------------------------------------------------------------------
// Pre-pass: W [D][E] fp32 -> fragment-major hi/lo fp16 tiles (lo scaled 2048).
// wint halfs layout: [t 0..63][f 0..3][h 0..1][lane 0..63][j 0..7]
//   element = {hi,lo}( W[k = t*32 + (lane>>4)*8 + j][e = f*16 + (lane&15)] )
// -> main-kernel B-fragment ds_read is per-lane contiguous 16B; staging is a
//    pure linear 8 KB global_load_lds copy. 512 KB in d_ws, L2-resident.
// ---------------------------------------------------------------------------
__global__ __launch_bounds__(64)
void wsplit_kernel(const float* __restrict__ W, _Float16* __restrict__ wint)
{
    const int b = blockIdx.x;            // 0..255 : t = b>>2, f = b&3
    const int t = b >> 2, f = b & 3;
    const int lane = threadIdx.x;        // one wave
    const int rr = lane & 15, kg = lane >> 4;
    half8 vh, vl;
#pragma unroll
    for (int j = 0; j < 8; ++j) {
        const float v = W[(size_t)(t * 32 + kg * 8 + j) * NEXP + f * 16 + rr];
        const _Float16 h = (_Float16)v;
        vh[j] = h;
        vl[j] = (_Float16)((v - (float)h) * 2048.0f);
    }
    *(half8*)(wint + ((size_t)b * 2 + 0) * 512 + lane * 8) = vh;
    *(half8*)(wint + ((size_t)b * 2 + 1) * 512 + lane * 8) = vl;
}

// ---------------------------------------------------------------------------
// Main: 512 blocks x 256 thr (4 waves). Wave (mt,eq) owns 16 rows x 32 experts,
// sweeps full K. 2-phase double-buffered async staging (global_load_lds),
// counted vmcnt(3), raw s_barrier — compiler cannot re-serialize this.
//   x tile: rows staged as 128B runs, chunk-XOR pre-swizzled at the SOURCE
//           (LDS dest linear), read back swizzled -> 2-way banks only.
//   W tile: fragment-major (pre-pass) -> linear stage, contiguous ds_read.
//   frag maps (HW-verified rounds 1/3): A row=lane&15, k=(lane>>4)*8+j;
//   B col=lane&15; D col=lane&15, row=(lane>>4)*4+reg.
// ---------------------------------------------------------------------------
__global__ __launch_bounds__(256)
void router_mfma(const float* __restrict__ x, const _Float16* __restrict__ wint,
                 const float* __restrict__ bias, const float* __restrict__ noise,
                 float* __restrict__ out)
{
    __shared__ char  sbuf[2][TBYTES];     // 24 KB: x at [0,4K), W at [4K,12K)
    __shared__ float pbuf[RPB][PADE];     // 8.7 KB logits assembly

    const int tid  = threadIdx.x;
    const int lane = tid & 63;
    const int wv   = __builtin_amdgcn_readfirstlane(tid >> 6);  // 0..3
    const int row0 = blockIdx.x * RPB;
    const int rr   = lane & 15, kg = lane >> 4;
    const int mt   = wv >> 1, eq = wv & 1;

    // ---- stage plan: 12 instrs/tile = [x0..x3, W0..W7]; wave issues 3 ----
    const int i0 = wv * 3;
    const char* sbase[3];
    int ldsoff[3], sstep[3];
#pragma unroll
    for (int q = 0; q < 3; ++q) {
        const int i = i0 + q;
        if (i < 4) {           // x rows i*8..i*8+7 ; lane -> (row=lane>>3, c=lane&7)
            const int row = i * 8 + (lane >> 3);
            const int c   = (lane & 7) ^ (row & 7);          // source pre-swizzle
            sbase[q]  = (const char*)(x + (size_t)(row0 + row) * DDIM + c * 4);
            ldsoff[q] = i * 1024;
            sstep[q]  = KTILE * 4;       // 128 B per K-tile
        } else {               // W: contiguous 1 KB slices of the 8 KB tile
            sbase[q]  = (const char*)(wint + (size_t)(i - 4) * 512 + lane * 8);
            ldsoff[q] = XBYTES + (i - 4) * 1024;
            sstep[q]  = WBYTES;          // 8192 B per K-tile
        }
    }

    // ---- read offsets (bytes within sbuf[b]) ----
    const int arow  = mt * 16 + rr;
    const int aoff0 = arow * 128 + (((2 * kg + 0) ^ (rr & 7)) * 16);
    const int aoff1 = arow * 128 + (((2 * kg + 1) ^ (rr & 7)) * 16);
    const int f0    = eq * 2;
    const int boh0  = XBYTES + (f0    ) * 2048 +        lane * 16;
    const int bol0  = XBYTES + (f0    ) * 2048 + 1024 + lane * 16;
    const int boh1  = XBYTES + (f0 + 1) * 2048 +        lane * 16;
    const int bol1  = XBYTES + (f0 + 1) * 2048 + 1024 + lane * 16;

    floatx4 acc0  = (floatx4){0.f, 0.f, 0.f, 0.f}, acc1  = acc0;
    floatx4 accl0 = acc0, accl1 = acc0;

#define STAGE(t, b) do { _Pragma("unroll") \
    for (int q = 0; q < 3; ++q) \
        gload_lds16(sbase[q] + (size_t)(t) * sstep[q], &sbuf[b][ldsoff[q]]); \
    } while (0)

#define LOOPBODY(t, b, VM) do { \
    if ((t) + 1 < NKT) STAGE((t) + 1, (b) ^ 1); \
    asm volatile("s_waitcnt vmcnt(" #VM ")" ::: "memory"); \
    __builtin_amdgcn_sched_barrier(0); \
    __builtin_amdgcn_s_barrier();                       /* buf b staged */ \
    const floatx4 xa  = *(const floatx4*)&sbuf[b][aoff0]; \
    const floatx4 xb  = *(const floatx4*)&sbuf[b][aoff1]; \
    const half8   bh0 = *(const half8*)&sbuf[b][boh0]; \
    const half8   bl0 = *(const half8*)&sbuf[b][bol0]; \
    const half8   bh1 = *(const half8*)&sbuf[b][boh1]; \
    const half8   bl1 = *(const half8*)&sbuf[b][bol1]; \
    asm volatile("s_waitcnt lgkmcnt(0)" ::: "memory"); \
    __builtin_amdgcn_sched_barrier(0); \
    __builtin_amdgcn_s_barrier();                       /* reads done: buf free */ \
    half8 ah, al; \
    _Pragma("unroll") \
    for (int ii = 0; ii < 4; ++ii) { \
        _Float16 h; float v; \
        v = xa[ii]; h = (_Float16)v; ah[ii]     = h; al[ii]     = (_Float16)((v - (float)h) * 2048.0f); \
        v = xb[ii]; h = (_Float16)v; ah[4 + ii] = h; al[4 + ii] = (_Float16)((v - (float)h) * 2048.0f); \
    } \
    acc0  = __builtin_amdgcn_mfma_f32_16x16x32_f16(ah, bh0, acc0,  0, 0, 0); \
    accl0 = __builtin_amdgcn_mfma_f32_16x16x32_f16(al, bh0, accl0, 0, 0, 0); \
    accl0 = __builtin_amdgcn_mfma_f32_16x16x32_f16(ah, bl0, accl0, 0, 0, 0); \
    acc1  = __builtin_amdgcn_mfma_f32_16x16x32_f16(ah, bh1, acc1,  0, 0, 0); \
    accl1 = __builtin_amdgcn_mfma_f32_16x16x32_f16(al, bh1, accl1, 0, 0, 0); \
    accl1 = __builtin_amdgcn_mfma_f32_16x16x32_f16(ah, bl1, accl1, 0, 0, 0); \
    } while (0)

    STAGE(0, 0);                                // prologue
#pragma unroll 1
    for (int t = 0; t < NKT - 1; ++t) {
        LOOPBODY(t, t & 1, 3);
    }
    LOOPBODY(NKT - 1, (NKT - 1) & 1, 0);        // tail: drain
#undef STAGE
#undef LOOPBODY

    // ---- deposit logits: row = mt*16 + kg*4 + r, col = eq*32 + et*16 + rr
    const float inv = 1.0f / 2048.0f;
#pragma unroll
    for (int r = 0; r < 4; ++r) {
        pbuf[mt * 16 + kg * 4 + r][eq * 32 +      rr] = acc0[r] + accl0[r] * inv;
        pbuf[mt * 16 + kg * 4 + r][eq * 32 + 16 + rr] = acc1[r] + accl1[r] * inv;
    }
    __syncthreads();

    // ---------------- epilogue: 8 rows per wave, all cross-lane ------------
    const float blane = bias[lane];
    float* const scores_out = out + 2 * BS_TOT * TOPK;
    float* const iout       = out + BS_TOT * TOPK;

#pragma unroll
    for (int j = 0; j < RPB / NWV; ++j) {
        const int rl = wv * (RPB / NWV) + j;
        const int r2 = row0 + rl;
        const float v = pbuf[rl][lane] + blane + 0.1f * noise[(size_t)r2 * NEXP + lane];

        float m = v;
#pragma unroll
        for (int off = 1; off < 64; off <<= 1) m = fmaxf(m, __shfl_xor(m, off));
        const float p = __expf(v - m);
        float s = p;
#pragma unroll
        for (int off = 1; off < 64; off <<= 1) s += __shfl_xor(s, off);
        const float sc = p * (1.0f / s);

        scores_out[(size_t)r2 * NEXP + lane] = sc;   // 256B coalesced

        // top-2 across 64 lanes on logits (order-identical to scores),
        // ties -> lower index (matches jax.lax.top_k).
        float a1 = v, a2 = -INFINITY;
        int   i1 = lane, i2 = 0x7fffffff;
#pragma unroll
        for (int off = 1; off < 64; off <<= 1) {
            const float o1 = __shfl_xor(a1, off), o2 = __shfl_xor(a2, off);
            const int  oi1 = __shfl_xor(i1, off), oi2 = __shfl_xor(i2, off);
            if (o1 > a1 || (o1 == a1 && oi1 < i1)) {
                if (a1 > o2 || (a1 == o2 && i1 < oi2)) { a2 = a1; i2 = i1; }
                else                                   { a2 = o2; i2 = oi2; }
                a1 = o1; i1 = oi1;
            } else {
                if (o1 > a2 || (o1 == a2 && oi1 < i2)) { a2 = o1; i2 = oi1; }
            }
        }
        const float s1 = __shfl(sc, i1);   // bitwise == scores entries
        const float s2 = __shfl(sc, i2);
        if (lane == 0) {
            out[(size_t)r2 * TOPK + 0]  = s1;
            out[(size_t)r2 * TOPK + 1]  = s2;
            iout[(size_t)r2 * TOPK + 0] = (float)i1;
            iout[(size_t)r2 * TOPK + 1] = (float)i2;
        }
    }
}

extern "C" void kernel_launch(void* const* d_in, const int* in_sizes, int n_in,
                              void* d_out, int out_size, void* d_ws, size_t ws_size,
                              hipStream_t stream)
{
    const float* x     = (const float*)d_in[0];
    const float* W     = (const float*)d_in[1];
    const float* bias  = (const float*)d_in[2];
    const float* noise = (const float*)d_in[3];
    float* out = (float*)d_out;
    (void)in_sizes; (void)n_in; (void)out_size; (void)ws_size;

    _Float16* wint = (_Float16*)d_ws;            // 512 KB fragment-major hi/lo

    hipLaunchKernelGGL(wsplit_kernel, dim3(256), dim3(64), 0, stream, W, wint);
    hipLaunchKernelGGL(router_mfma, dim3(BS_TOT / RPB), dim3(256), 0, stream,
                       x, wint, bias, noise, out);
}

// Round 5
// 218.573 us; speedup vs baseline: 1.0829x; 1.0829x over previous
//
#include <hip/hip_runtime.h>
#include <math.h>

// Problem constants (B=4, S=4096, D=2048, E=64, K=2)
#define BS_TOT 16384
#define DDIM   2048
#define NEXP   64
#define TOPK   2

#define RPB    32                // rows per block
#define SK     64                // k per subtile (phase)
#define NST    (DDIM / SK)       // 32 phases
#define PADE   68

typedef _Float16 half8   __attribute__((ext_vector_type(8)));
typedef _Float16 half4   __attribute__((ext_vector_type(4)));
typedef float    floatx4 __attribute__((ext_vector_type(4)));

// ---------------------------------------------------------------------------
// Pre-pass (verbatim from R4, HW-verified layout): W [D][E] fp32 ->
// fragment-major hi/lo fp16 (lo scaled 2048).
// halfs index: t*4096 + f*1024 + h*512 + lane*8 + j  where
//   element = {hi,lo}( W[k = t*32 + (lane>>4)*8 + j][e = f*16 + (lane&15)] )
// ---------------------------------------------------------------------------
__global__ __launch_bounds__(64)
void wsplit_kernel(const float* __restrict__ W, _Float16* __restrict__ wint)
{
    const int b = blockIdx.x;            // 0..255 : t = b>>2, f = b&3
    const int t = b >> 2, f = b & 3;
    const int lane = threadIdx.x;        // one wave
    const int rr = lane & 15, kg = lane >> 4;
    half8 vh, vl;
#pragma unroll
    for (int j = 0; j < 8; ++j) {
        const float v = W[(size_t)(t * 32 + kg * 8 + j) * NEXP + f * 16 + rr];
        const _Float16 h = (_Float16)v;
        vh[j] = h;
        vl[j] = (_Float16)((v - (float)h) * 2048.0f);
    }
    *(half8*)(wint + ((size_t)b * 2 + 0) * 512 + lane * 8) = vh;
    *(half8*)(wint + ((size_t)b * 2 + 1) * 512 + lane * 8) = vl;
}

// ---------------------------------------------------------------------------
// Main: 512 blocks x 256 thr (4 waves). Wave (mh,eg) owns 16 rows x 32
// experts, sweeps full K in 32 phases of 64 k. Per phase:
//   issue x(s+3) coalesced fp32 loads -> reg ring (3 phases of flight)
//   issue B(s+1) direct reg loads from fragment-major wint (L2, coalesced)
//   compute subtile s: 4 swizzled ds_read_b128 + 12 MFMA (3-pass hi/lo)
//   cvt x(s+1) fp32->f16 hi/lo, ds_write to swizzled LDS planes
//   lgkmcnt(0) + s_barrier  (ONE barrier per phase)
// All loads have dest regs -> compiler emits exact counted vmcnt's; phase
// boundaries pinned by asm memory clobbers. No K-split -> no reduction.
// ---------------------------------------------------------------------------
__global__ __launch_bounds__(256, 3)
void router_mfma(const float* __restrict__ x, const _Float16* __restrict__ wint,
                 const float* __restrict__ bias, const float* __restrict__ noise,
                 float* __restrict__ out)
{
    __shared__ _Float16 xh[2][RPB][SK];   // 8 KB hi plane (granule-XOR swizzled)
    __shared__ _Float16 xl[2][RPB][SK];   // 8 KB lo plane
    __shared__ float    pbuf[RPB][PADE];  // 8.7 KB logits assembly

    const int tid  = threadIdx.x;
    const int lane = tid & 63;
    const int wv   = __builtin_amdgcn_readfirstlane(tid >> 6);  // 0..3
    const int eg   = wv & 1;            // expert half (32 e)
    const int mh   = wv >> 1;           // row half (16 r)
    const int rr   = lane & 15, kg = lane >> 4;
    const int row0 = blockIdx.x * RPB;

    // x staging: instr h(0/1): lane -> row = wv*8 + h*4 + (lane>>4), chunk cc = lane&15
    const float* xb0 = x + (size_t)(row0 + wv * 8 + (lane >> 4)) * DDIM + (lane & 15) * 4;
    const float* xb1 = xb0 + (size_t)4 * DDIM;
    // cvt/write: thread owns (row r, chunk cc) for h=0,1; swizzled granule:
    //   half-off(r,cc) = ((cc>>1)^(r&7))*8 + (cc&1)*4
    const int cc    = lane & 15;
    const int wr0   = wv * 8 + (lane >> 4);

    // A-frag read (lane rr,kg; row = mh*16+rr): granule g = kk*4+kg, swz ^(rr&7)
    const int arow = mh * 16 + rr;

    floatx4 gx[4][2];                 // x reg ring, 3 phases deep
    half8 bh[2][2][2], bl[2][2][2];   // B ring [st&1][kk][ff]
    floatx4 acc[2], accl[2];
#pragma unroll
    for (int ff = 0; ff < 2; ++ff) {
        acc[ff]  = (floatx4){0.f, 0.f, 0.f, 0.f};
        accl[ff] = acc[ff];
    }

#define ISSUE_X(ss) do { \
        gx[(ss) & 3][0] = *(const floatx4*)(xb0 + (ss) * SK); \
        gx[(ss) & 3][1] = *(const floatx4*)(xb1 + (ss) * SK); } while (0)

#define ISSUE_B(st) do { \
        const _Float16* wb = wint + (size_t)(2 * (st)) * 4096 + eg * 2048 + lane * 8; \
        _Pragma("unroll") \
        for (int kk = 0; kk < 2; ++kk) \
        _Pragma("unroll") \
        for (int ff = 0; ff < 2; ++ff) { \
            bh[(st) & 1][kk][ff] = *(const half8*)(wb + kk * 4096 + ff * 1024); \
            bl[(st) & 1][kk][ff] = *(const half8*)(wb + kk * 4096 + ff * 1024 + 512); \
        } } while (0)

#define CVT_X(sp) do { \
        _Pragma("unroll") \
        for (int h = 0; h < 2; ++h) { \
            const floatx4 v = gx[(sp) & 3][h]; \
            const int r = wr0 + h * 4; \
            half4 vh, vl4; \
            _Pragma("unroll") \
            for (int j = 0; j < 4; ++j) { \
                const _Float16 hh = (_Float16)v[j]; \
                vh[j]  = hh; \
                vl4[j] = (_Float16)((v[j] - (float)hh) * 2048.0f); \
            } \
            const int go = (((cc >> 1) ^ (r & 7)) << 3) + ((cc & 1) << 2); \
            *(half4*)&xh[(sp) & 1][r][go] = vh; \
            *(half4*)&xl[(sp) & 1][r][go] = vl4; \
        } } while (0)

#define PHASE_BAR() asm volatile("s_waitcnt lgkmcnt(0)\n\ts_barrier" ::: "memory")

    // ---- prologue: x(0..2) + B(0) in flight; cvt x(0); publish ----
    ISSUE_X(0); ISSUE_X(1); ISSUE_X(2);
    ISSUE_B(0);
    CVT_X(0);
    PHASE_BAR();

#pragma unroll 4
    for (int s = 0; s < NST; ++s) {
        if (s + 3 < NST) ISSUE_X(s + 3);
        if (s + 1 < NST) ISSUE_B(s + 1);
        // ---- compute subtile s ----
#pragma unroll
        for (int kk = 0; kk < 2; ++kk) {
            const int go = ((kk * 4 + kg) ^ (rr & 7)) << 3;
            const half8 ah = *(const half8*)&xh[s & 1][arow][go];
            const half8 al = *(const half8*)&xl[s & 1][arow][go];
#pragma unroll
            for (int ff = 0; ff < 2; ++ff) {
                acc[ff]  = __builtin_amdgcn_mfma_f32_16x16x32_f16(ah, bh[s & 1][kk][ff], acc[ff],  0, 0, 0);
                accl[ff] = __builtin_amdgcn_mfma_f32_16x16x32_f16(al, bh[s & 1][kk][ff], accl[ff], 0, 0, 0);
                accl[ff] = __builtin_amdgcn_mfma_f32_16x16x32_f16(ah, bl[s & 1][kk][ff], accl[ff], 0, 0, 0);
            }
        }
        if (s + 1 < NST) CVT_X(s + 1);
        PHASE_BAR();
    }
#undef ISSUE_X
#undef ISSUE_B
#undef CVT_X
#undef PHASE_BAR

    // ---- deposit logits: row = mh*16 + kg*4 + r, col = (eg*2+ff)*16 + rr
    const float inv = 1.0f / 2048.0f;
#pragma unroll
    for (int ff = 0; ff < 2; ++ff)
#pragma unroll
        for (int r = 0; r < 4; ++r)
            pbuf[mh * 16 + kg * 4 + r][(eg * 2 + ff) * 16 + rr] =
                acc[ff][r] + accl[ff][r] * inv;
    __syncthreads();

    // ---------------- epilogue: 8 rows per wave, all cross-lane ------------
    const float blane = bias[lane];
    float* const scores_out = out + 2 * BS_TOT * TOPK;
    float* const iout       = out + BS_TOT * TOPK;

#pragma unroll
    for (int j = 0; j < RPB / 4; ++j) {
        const int rl = wv * (RPB / 4) + j;
        const int r2 = row0 + rl;
        const float v = pbuf[rl][lane] + blane + 0.1f * noise[(size_t)r2 * NEXP + lane];

        float m = v;
#pragma unroll
        for (int off = 1; off < 64; off <<= 1) m = fmaxf(m, __shfl_xor(m, off));
        const float p = __expf(v - m);
        float s = p;
#pragma unroll
        for (int off = 1; off < 64; off <<= 1) s += __shfl_xor(s, off);
        const float sc = p * (1.0f / s);

        scores_out[(size_t)r2 * NEXP + lane] = sc;   // 256B coalesced

        // top-2 across 64 lanes on logits (order-identical to scores),
        // ties -> lower index (matches jax.lax.top_k).
        float a1 = v, a2 = -INFINITY;
        int   i1 = lane, i2 = 0x7fffffff;
#pragma unroll
        for (int off = 1; off < 64; off <<= 1) {
            const float o1 = __shfl_xor(a1, off), o2 = __shfl_xor(a2, off);
            const int  oi1 = __shfl_xor(i1, off), oi2 = __shfl_xor(i2, off);
            if (o1 > a1 || (o1 == a1 && oi1 < i1)) {
                if (a1 > o2 || (a1 == o2 && i1 < oi2)) { a2 = a1; i2 = i1; }
                else                                   { a2 = o2; i2 = oi2; }
                a1 = o1; i1 = oi1;
            } else {
                if (o1 > a2 || (o1 == a2 && oi1 < i2)) { a2 = o1; i2 = oi1; }
            }
        }
        const float s1 = __shfl(sc, i1);   // bitwise == scores entries
        const float s2 = __shfl(sc, i2);
        if (lane == 0) {
            out[(size_t)r2 * TOPK + 0]  = s1;
            out[(size_t)r2 * TOPK + 1]  = s2;
            iout[(size_t)r2 * TOPK + 0] = (float)i1;
            iout[(size_t)r2 * TOPK + 1] = (float)i2;
        }
    }
}

extern "C" void kernel_launch(void* const* d_in, const int* in_sizes, int n_in,
                              void* d_out, int out_size, void* d_ws, size_t ws_size,
                              hipStream_t stream)
{
    const float* x     = (const float*)d_in[0];
    const float* W     = (const float*)d_in[1];
    const float* bias  = (const float*)d_in[2];
    const float* noise = (const float*)d_in[3];
    float* out = (float*)d_out;
    (void)in_sizes; (void)n_in; (void)out_size; (void)ws_size;

    _Float16* wint = (_Float16*)d_ws;            // 512 KB fragment-major hi/lo

    hipLaunchKernelGGL(wsplit_kernel, dim3(256), dim3(64), 0, stream, W, wint);
    hipLaunchKernelGGL(router_mfma, dim3(BS_TOT / RPB), dim3(256), 0, stream,
                       x, wint, bias, noise, out);
}